// Round 1
// baseline (3157.677 us; speedup 1.0000x reference)
//
#include <hip/hip_runtime.h>
#include <math.h>

#define BATCH 32
#define TFRAMES 1024
#define NBINS 257
#define NFFT 512
#define HOP 160
#define LOUT 163680            // (T-1)*HOP
#define XPLEN 164192           // LOUT + NFFT
#define NITER 32

// LDS padding: every 4 floats insert 1 -> breaks power-of-2 bank strides
#define P4(i) ((i) + ((i) >> 2))

// ---- ws layout (float offsets) ----
#define OFF_FRAMES ((size_t)0)
#define SZ_FRAMES  ((size_t)BATCH * TFRAMES * NFFT)        // 16777216
#define OFF_XP     (OFF_FRAMES + SZ_FRAMES)
#define SZ_XP      ((size_t)BATCH * XPLEN)                 // 5254144
#define OFF_ANG    (OFF_XP + SZ_XP)
#define SZ_ANG     ((size_t)BATCH * TFRAMES * NBINS)       // 8421376
#define OFF_TWC    (OFF_ANG + SZ_ANG)
#define OFF_TWS    (OFF_TWC + 512)
#define OFF_WSQI   (OFF_TWS + 512)

// ============================================================
// init: twiddle table (double-precision trig) + 1/wsq (NOLA)
// ============================================================
__global__ __launch_bounds__(256) void k_init(const float* __restrict__ win,
                                              float* __restrict__ twc,
                                              float* __restrict__ tws,
                                              float* __restrict__ wsqi) {
    int i = blockIdx.x * 256 + threadIdx.x;
    if (i < 512) {
        double th = (6.283185307179586476925286766559 / 512.0) * (double)i;
        twc[i] = (float)cos(th);
        tws[i] = (float)sin(th);
    }
    if (i < XPLEN) {
        int n = i;
        int tmax = n / HOP; if (tmax > TFRAMES - 1) tmax = TFRAMES - 1;
        int tmin = (n - (NFFT - 1) + (HOP - 1)) / HOP; if (tmin < 0) tmin = 0;
        float acc = 0.f;
        for (int t = tmin; t <= tmax; ++t) {
            float w = win[n - t * HOP];
            acc += w * w;
        }
        wsqi[i] = 1.0f / (acc > 1e-11f ? acc : 1.0f);
    }
}

// ============================================================
// 256-point complex FFT per wave64, radix-4 Stockham, 4 levels.
// SIGN=-1: forward (e^{-i}); SIGN=+1: inverse (e^{+i}), NO 1/N scale.
// Input in (Ar,Ai) natural order; output in (Ar,Ai) natural order.
// ============================================================
template<int SIGN>
__device__ __forceinline__ void fft256_wave(float* Ar, float* Ai,
                                            float* Br, float* Bi,
                                            const float* __restrict__ twc,
                                            const float* __restrict__ tws,
                                            int lane) {
    constexpr float SG = (SIGN > 0) ? 1.f : -1.f;
    float *sr = Ar, *si = Ai, *dr = Br, *di = Bi;
    int s = 1;
#pragma unroll
    for (int lev = 0; lev < 4; ++lev) {
        int p = lane >> (2 * lev);
        int q = lane & (s - 1);
        float a_re = sr[P4(lane)],       a_im = si[P4(lane)];
        float b_re = sr[P4(lane + 64)],  b_im = si[P4(lane + 64)];
        float c_re = sr[P4(lane + 128)], c_im = si[P4(lane + 128)];
        float d_re = sr[P4(lane + 192)], d_im = si[P4(lane + 192)];

        float apc_re = a_re + c_re, apc_im = a_im + c_im;
        float amc_re = a_re - c_re, amc_im = a_im - c_im;
        float bpd_re = b_re + d_re, bpd_im = b_im + d_im;
        float bmd_re = b_re - d_re, bmd_im = b_im - d_im;

        float y0_re = apc_re + bpd_re, y0_im = apc_im + bpd_im;
        float y2_re = apc_re - bpd_re, y2_im = apc_im - bpd_im;
        // y1 = amc + SG*i*bmd ; y3 = amc - SG*i*bmd
        float y1_re = amc_re - SG * bmd_im, y1_im = amc_im + SG * bmd_re;
        float y3_re = amc_re + SG * bmd_im, y3_im = amc_im - SG * bmd_re;

        int j1 = p << (2 * lev + 1);      // twiddle index in units of 2pi/512
        int j2 = j1 + j1, j3 = j2 + j1;
        float w1c = twc[j1], w1s = SG * tws[j1];
        float w2c = twc[j2], w2s = SG * tws[j2];
        float w3c = twc[j3], w3s = SG * tws[j3];

        int o0 = q + s * 4 * p;
        dr[P4(o0)]         = y0_re;
        di[P4(o0)]         = y0_im;
        dr[P4(o0 + s)]     = w1c * y1_re - w1s * y1_im;
        di[P4(o0 + s)]     = w1c * y1_im + w1s * y1_re;
        dr[P4(o0 + 2 * s)] = w2c * y2_re - w2s * y2_im;
        di[P4(o0 + 2 * s)] = w2c * y2_im + w2s * y2_re;
        dr[P4(o0 + 3 * s)] = w3c * y3_re - w3s * y3_im;
        di[P4(o0 + 3 * s)] = w3c * y3_im + w3s * y3_re;
        __syncthreads();
        float* tp = sr; sr = dr; dr = tp;
        tp = si; si = di; di = tp;
        s <<= 2;
    }
    // after 4 swaps result is back in (Ar, Ai)
}

// ============================================================
// K_inv: spec = mag*e^{i*ang} -> irfft(512) -> *window/512 -> frames
// one wave64 per frame; 4 frames per 256-thread block
// ============================================================
__global__ __launch_bounds__(256) void k_inv(const float* __restrict__ mag,
                                             const float* __restrict__ ang,
                                             const float* __restrict__ win,
                                             const float* __restrict__ twc,
                                             const float* __restrict__ tws,
                                             float* __restrict__ frames) {
    __shared__ float sAr[4][324], sAi[4][324], sBr[4][324], sBi[4][324];
    __shared__ float stc[512], sts[512], swin[512];
    int tid = threadIdx.x, w = tid >> 6, lane = tid & 63;
    for (int i = tid; i < 512; i += 256) { stc[i] = twc[i]; sts[i] = tws[i]; swin[i] = win[i]; }

    int frame = blockIdx.x * 4 + w;
    const float* magp = mag + (size_t)frame * NBINS;
    const float* angp = ang + (size_t)frame * NBINS;
    float *Ar = sAr[w], *Ai = sAi[w], *Br = sBr[w], *Bi = sBi[w];

    // stage half-spectrum X into B (imag of DC/Nyquist ignored, like c2r)
#pragma unroll
    for (int r = 0; r < 4; ++r) {
        int k = lane + 64 * r;
        float m = magp[k], a = angp[k];
        float sn, cs;
        sincosf(a, &sn, &cs);
        float xr = m * cs, xi = m * sn;
        if (k == 0) xi = 0.f;
        Br[P4(k)] = xr; Bi[P4(k)] = xi;
    }
    if (lane == 0) {
        float m = magp[256], a = angp[256];
        Br[P4(256)] = m * cosf(a);
        Bi[P4(256)] = 0.f;
    }
    __syncthreads();

    // pack: Z[k] = Xe[k] + i*Xo[k]
#pragma unroll
    for (int r = 0; r < 4; ++r) {
        int k = lane + 64 * r;
        int mk = 256 - k;
        float xr = Br[P4(k)],  xi = Bi[P4(k)];
        float yr = Br[P4(mk)], yi = Bi[P4(mk)];
        float Xer = 0.5f * (xr + yr), Xei = 0.5f * (xi - yi);
        float Dr = xr - yr, Di = xi + yi;
        float tc = stc[k], ts = sts[k];           // e^{+2pi i k/512}
        float Xor = 0.5f * (tc * Dr - ts * Di);
        float Xoi = 0.5f * (tc * Di + ts * Dr);
        Ar[P4(k)] = Xer - Xoi;
        Ai[P4(k)] = Xei + Xor;
    }
    __syncthreads();

    fft256_wave<+1>(Ar, Ai, Br, Bi, stc, sts, lane);

    float* fp = frames + (size_t)frame * NFFT;
    constexpr float SC = 1.f / 256.f;             // with the 1/2 in Xe/Xo => 1/512 total
#pragma unroll
    for (int r = 0; r < 4; ++r) {
        int m = lane + 64 * r;
        float zr = Ar[P4(m)], zi = Ai[P4(m)];
        float2 o = make_float2(zr * swin[2 * m] * SC, zi * swin[2 * m + 1] * SC);
        reinterpret_cast<float2*>(fp)[m] = o;
    }
}

// ============================================================
// K_ola: overlap-add + NOLA normalize (+ reflect-pad for mode 0)
// mode 0: out = xp [B][XPLEN] ; mode 1: out = d_out [B][LOUT]
// ============================================================
__global__ __launch_bounds__(256) void k_ola(const float* __restrict__ frames,
                                             const float* __restrict__ wsqi,
                                             float* __restrict__ out, int mode) {
    int plen = mode ? LOUT : XPLEN;
    long long gid = (long long)blockIdx.x * 256 + threadIdx.x;
    if (gid >= (long long)BATCH * plen) return;
    int b = (int)(gid / plen), p = (int)(gid % plen);
    int q = mode ? p : p - 256;
    if (q < 0) q = -q;
    else if (q >= LOUT) q = 2 * LOUT - 2 - q;
    int n = q + 256;
    int tmax = n / HOP; if (tmax > TFRAMES - 1) tmax = TFRAMES - 1;
    int tmin = (n - (NFFT - 1) + (HOP - 1)) / HOP; if (tmin < 0) tmin = 0;
    const float* fb = frames + (size_t)b * TFRAMES * NFFT;
    float acc = 0.f;
    for (int t = tmin; t <= tmax; ++t) acc += fb[(size_t)t * NFFT + (n - t * HOP)];
    out[gid] = acc * wsqi[n];
}

// ============================================================
// K_fwd: frame from padded wave -> *window -> rfft(512) -> atan2 -> angles
// ============================================================
__global__ __launch_bounds__(256) void k_fwd(const float* __restrict__ xp,
                                             const float* __restrict__ win,
                                             const float* __restrict__ twc,
                                             const float* __restrict__ tws,
                                             float* __restrict__ ang) {
    __shared__ float sAr[4][324], sAi[4][324], sBr[4][324], sBi[4][324];
    __shared__ float stc[512], sts[512], swin[512];
    int tid = threadIdx.x, w = tid >> 6, lane = tid & 63;
    for (int i = tid; i < 512; i += 256) { stc[i] = twc[i]; sts[i] = tws[i]; swin[i] = win[i]; }
    __syncthreads();

    int frame = blockIdx.x * 4 + w;
    int b = frame >> 10, t = frame & (TFRAMES - 1);
    const float2* src = reinterpret_cast<const float2*>(xp + (size_t)b * XPLEN + (size_t)t * HOP);
    float *Ar = sAr[w], *Ai = sAi[w], *Br = sBr[w], *Bi = sBi[w];

#pragma unroll
    for (int r = 0; r < 4; ++r) {
        int m = lane + 64 * r;
        float2 v = src[m];
        Ar[P4(m)] = v.x * swin[2 * m];
        Ai[P4(m)] = v.y * swin[2 * m + 1];
    }
    __syncthreads();

    fft256_wave<-1>(Ar, Ai, Br, Bi, stc, sts, lane);

    float* angp = ang + (size_t)frame * NBINS;
#pragma unroll
    for (int r = 0; r < 4; ++r) {
        int k = lane + 64 * r;
        int mk = (256 - k) & 255;
        float zr = Ar[P4(k)],  zi = Ai[P4(k)];
        float yr = Ar[P4(mk)], yi = Ai[P4(mk)];
        float Xer = 0.5f * (zr + yr), Xei = 0.5f * (zi - yi);
        float Dr = zr - yr, Di = zi + yi;
        float Xor = 0.5f * Di, Xoi = -0.5f * Dr;   // -i*D/2
        float tc = stc[k], ts = sts[k];            // e^{-2pi i k/512} = (tc, -ts)
        float Xre = Xer + tc * Xor + ts * Xoi;
        float Xim = Xei + tc * Xoi - ts * Xor;
        if (k == 0) Xim = 0.f;
        angp[k] = atan2f(Xim, Xre);
    }
    if (lane == 0) {
        float zr = Ar[P4(0)], zi = Ai[P4(0)];
        angp[256] = atan2f(0.f, zr - zi);           // Nyquist: real
    }
}

// ============================================================
extern "C" void kernel_launch(void* const* d_in, const int* in_sizes, int n_in,
                              void* d_out, int out_size, void* d_ws, size_t ws_size,
                              hipStream_t stream) {
    const float* mag  = (const float*)d_in[0];
    const float* ang0 = (const float*)d_in[1];
    const float* win  = (const float*)d_in[2];
    float* ws     = (float*)d_ws;
    float* frames = ws + OFF_FRAMES;
    float* xp     = ws + OFF_XP;
    float* angw   = ws + OFF_ANG;
    float* twc    = ws + OFF_TWC;
    float* tws    = ws + OFF_TWS;
    float* wsqi   = ws + OFF_WSQI;
    float* outp   = (float*)d_out;

    k_init<<<(XPLEN + 255) / 256, 256, 0, stream>>>(win, twc, tws, wsqi);

    const int fblocks = BATCH * TFRAMES / 4;   // 8192
    for (int it = 0; it < NITER; ++it) {
        const float* a = (it == 0) ? ang0 : angw;
        k_inv<<<fblocks, 256, 0, stream>>>(mag, a, win, twc, tws, frames);
        k_ola<<<(BATCH * XPLEN + 255) / 256, 256, 0, stream>>>(frames, wsqi, xp, 0);
        k_fwd<<<fblocks, 256, 0, stream>>>(xp, win, twc, tws, angw);
    }
    // final istft with converged angles -> cropped output
    k_inv<<<fblocks, 256, 0, stream>>>(mag, angw, win, twc, tws, frames);
    k_ola<<<(BATCH * LOUT + 255) / 256, 256, 0, stream>>>(frames, wsqi, outp, 1);
}

// Round 2
// 2274.780 us; speedup vs baseline: 1.3881x; 1.3881x over previous
//
#include <hip/hip_runtime.h>
#include <math.h>

#define BATCH 32
#define TFRAMES 1024
#define NBINS 257
#define NFFT 512
#define HOP 160
#define LOUT 163680            // (T-1)*HOP
#define XPLEN 164192           // LOUT + NFFT
#define NITER 32

// LDS padding: one pad word per 32 -> all stride-1 / stride-64 wave patterns are
// exactly 2 lanes/bank (free per m136); only Stockham lev1/2 writes are 4-way.
#define P(i) ((i) + ((i) >> 5))

// ---- ws layout (float offsets) ----
#define OFF_FRAMES ((size_t)0)
#define SZ_FRAMES  ((size_t)BATCH * TFRAMES * NFFT)        // 16777216
#define OFF_XP     (OFF_FRAMES + SZ_FRAMES)
#define SZ_XP      ((size_t)BATCH * XPLEN)                 // 5254144
#define OFF_WSQI   (OFF_XP + SZ_XP)

// hardware trig: input in revolutions, args here always in [0, 0.75)
__device__ __forceinline__ float cosr(float x) { return __builtin_amdgcn_cosf(x); }
__device__ __forceinline__ float sinr(float x) { return __builtin_amdgcn_sinf(x); }

// wave-synchronous LDS: per-wave buffers, wave64 lockstep; fence keeps the
// compiler from reordering LDS ops across phases (no cross-wave sync needed)
__device__ __forceinline__ void wsync() {
    __builtin_amdgcn_fence(__ATOMIC_SEQ_CST, "wavefront");
    __builtin_amdgcn_wave_barrier();
}

// ============================================================
// init: 1/wsq (NOLA) only
// ============================================================
__global__ __launch_bounds__(256) void k_init(const float* __restrict__ win,
                                              float* __restrict__ wsqi) {
    int i = blockIdx.x * 256 + threadIdx.x;
    if (i < XPLEN) {
        int n = i;
        int tmax = n / HOP; if (tmax > TFRAMES - 1) tmax = TFRAMES - 1;
        int tmin = (n - (NFFT - 1) + (HOP - 1)) / HOP; if (tmin < 0) tmin = 0;
        float acc = 0.f;
        for (int t = tmin; t <= tmax; ++t) {
            float w = win[n - t * HOP];
            acc += w * w;
        }
        wsqi[i] = 1.0f / (acc > 1e-11f ? acc : 1.0f);
    }
}

// ============================================================
// 256-point complex FFT per wave64, radix-4 Stockham, 4 levels.
// SIGN=-1 fwd, SIGN=+1 inv (no 1/N). In/out natural order in (Ar,Ai).
// Twiddles computed via v_cos/v_sin on exact dyadic revolutions.
// ============================================================
template<int SIGN>
__device__ __forceinline__ void fft256(float* __restrict__ Ar, float* __restrict__ Ai,
                                       float* __restrict__ Br, float* __restrict__ Bi,
                                       int lane) {
    constexpr float SG = (SIGN > 0) ? 1.f : -1.f;
    float *sr = Ar, *si = Ai, *dr = Br, *di = Bi;
    int s = 1;
#pragma unroll
    for (int lev = 0; lev < 4; ++lev) {
        int p = lane >> (2 * lev);
        int q = lane & (s - 1);
        float a_re = sr[P(lane)],       a_im = si[P(lane)];
        float b_re = sr[P(lane + 64)],  b_im = si[P(lane + 64)];
        float c_re = sr[P(lane + 128)], c_im = si[P(lane + 128)];
        float d_re = sr[P(lane + 192)], d_im = si[P(lane + 192)];

        float apc_re = a_re + c_re, apc_im = a_im + c_im;
        float amc_re = a_re - c_re, amc_im = a_im - c_im;
        float bpd_re = b_re + d_re, bpd_im = b_im + d_im;
        float bmd_re = b_re - d_re, bmd_im = b_im - d_im;

        float y0_re = apc_re + bpd_re, y0_im = apc_im + bpd_im;
        float y2_re = apc_re - bpd_re, y2_im = apc_im - bpd_im;
        float y1_re = amc_re - SG * bmd_im, y1_im = amc_im + SG * bmd_re;
        float y3_re = amc_re + SG * bmd_im, y3_im = amc_im - SG * bmd_re;

        // twiddle W^j1, j1 = p<<(2lev+1) in 1/512 revs; j1/512 <= 0.246 -> HW-trig safe
        float x1 = (float)(p << (2 * lev + 1)) * (1.0f / 512.0f);
        float w1c = cosr(x1), w1s = SG * sinr(x1);
        float w2c = w1c * w1c - w1s * w1s, w2s = 2.0f * w1c * w1s;
        float w3c = w2c * w1c - w2s * w1s, w3s = w2c * w1s + w2s * w1c;

        int o0 = q + s * 4 * p;
        dr[P(o0)]         = y0_re;
        di[P(o0)]         = y0_im;
        dr[P(o0 + s)]     = w1c * y1_re - w1s * y1_im;
        di[P(o0 + s)]     = w1c * y1_im + w1s * y1_re;
        dr[P(o0 + 2 * s)] = w2c * y2_re - w2s * y2_im;
        di[P(o0 + 2 * s)] = w2c * y2_im + w2s * y2_re;
        dr[P(o0 + 3 * s)] = w3c * y3_re - w3s * y3_im;
        di[P(o0 + 3 * s)] = w3c * y3_im + w3s * y3_re;
        wsync();
        float* tp = sr; sr = dr; dr = tp;
        tp = si; si = di; di = tp;
        s <<= 2;
    }
    // 4 swaps -> result back in (Ar, Ai)
}

// ============================================================
// shared tail: S (spectrum, natural 0..256 in B) -> c2r pack -> inv FFT
// -> *window/512 -> frame store
// ============================================================
__device__ __forceinline__ void spec_to_frame(float* Ar, float* Ai,
                                              float* Br, float* Bi,
                                              const float2* swin2, int lane,
                                              float* __restrict__ fp) {
#pragma unroll
    for (int r = 0; r < 4; ++r) {
        int k = lane + 64 * r, mk = 256 - k;
        float xr = Br[P(k)],  xi = Bi[P(k)];
        float yr = Br[P(mk)], yi = Bi[P(mk)];
        float Xer = 0.5f * (xr + yr), Xei = 0.5f * (xi - yi);
        float Dr = xr - yr, Di = xi + yi;
        float xv = (float)k * (1.0f / 512.0f);       // e^{+2pi i k/512}
        float tc = cosr(xv), ts = sinr(xv);
        float Xor = 0.5f * (tc * Dr - ts * Di);
        float Xoi = 0.5f * (tc * Di + ts * Dr);
        Ar[P(k)] = Xer - Xoi;
        Ai[P(k)] = Xei + Xor;
    }
    wsync();
    fft256<+1>(Ar, Ai, Br, Bi, lane);
    constexpr float SC = 1.0f / 256.0f;              // total 1/512 with the 1/2 above
#pragma unroll
    for (int r = 0; r < 4; ++r) {
        int m = lane + 64 * r;
        float2 wv = swin2[m];
        float zr = Ar[P(m)], zi = Ai[P(m)];
        reinterpret_cast<float2*>(fp)[m] = make_float2(zr * wv.x * SC, zi * wv.y * SC);
    }
}

// ============================================================
// K_inv0: iteration-0 istft from (mag, angles_init)
// ============================================================
__global__ __launch_bounds__(256) void k_inv0(const float* __restrict__ mag,
                                              const float* __restrict__ ang,
                                              const float* __restrict__ win,
                                              float* __restrict__ frames) {
    __shared__ float sAr[4][272], sAi[4][272], sBr[4][272], sBi[4][272];
    __shared__ float2 swin2[256];
    int tid = threadIdx.x, w = tid >> 6, lane = tid & 63;
    if (tid < 256) swin2[tid] = make_float2(win[2 * tid], win[2 * tid + 1]);
    __syncthreads();

    int frame = blockIdx.x * 4 + w;
    const float* magp = mag + (size_t)frame * NBINS;
    const float* angp = ang + (size_t)frame * NBINS;
    float *Ar = sAr[w], *Ai = sAi[w], *Br = sBr[w], *Bi = sBi[w];

#pragma unroll
    for (int r = 0; r < 4; ++r) {
        int k = lane + 64 * r;
        float m = magp[k], a = angp[k];
        float sn, cs;
        sincosf(a, &sn, &cs);
        Br[P(k)] = m * cs;
        Bi[P(k)] = (k == 0) ? 0.f : m * sn;
    }
    if (lane == 0) {
        Br[P(256)] = magp[256] * cosf(angp[256]);
        Bi[P(256)] = 0.f;
    }
    wsync();
    spec_to_frame(Ar, Ai, Br, Bi, swin2, lane, frames + (size_t)frame * NFFT);
}

// ============================================================
// K_fused: xp -> frame -> rfft -> unit-phasor normalize -> *mag -> istft -> frames
// (replaces k_fwd + k_inv; no angles, no atan2, no sincos)
// ============================================================
__global__ __launch_bounds__(256) void k_fused(const float* __restrict__ xp,
                                               const float* __restrict__ mag,
                                               const float* __restrict__ win,
                                               float* __restrict__ frames) {
    __shared__ float sAr[4][272], sAi[4][272], sBr[4][272], sBi[4][272];
    __shared__ float2 swin2[256];
    int tid = threadIdx.x, w = tid >> 6, lane = tid & 63;
    if (tid < 256) swin2[tid] = make_float2(win[2 * tid], win[2 * tid + 1]);
    __syncthreads();

    int frame = blockIdx.x * 4 + w;
    int b = frame >> 10, t = frame & (TFRAMES - 1);
    const float2* src = reinterpret_cast<const float2*>(xp + (size_t)b * XPLEN) + t * (HOP / 2);
    float *Ar = sAr[w], *Ai = sAi[w], *Br = sBr[w], *Bi = sBi[w];

    // windowed frame, packed real pairs z[m] = x[2m] + i x[2m+1]
#pragma unroll
    for (int r = 0; r < 4; ++r) {
        int m = lane + 64 * r;
        float2 v = src[m];
        float2 wv = swin2[m];
        Ar[P(m)] = v.x * wv.x;
        Ai[P(m)] = v.y * wv.y;
    }
    wsync();

    fft256<-1>(Ar, Ai, Br, Bi, lane);

    // r2c unpack -> bin -> unit phasor (rsqrt) -> * mag -> S into B
    const float* magp = mag + (size_t)frame * NBINS;
#pragma unroll
    for (int r = 0; r < 4; ++r) {
        int k = lane + 64 * r;
        int mk = (256 - k) & 255;
        float zr = Ar[P(k)],  zi = Ai[P(k)];
        float yr = Ar[P(mk)], yi = Ai[P(mk)];
        float Xer = 0.5f * (zr + yr), Xei = 0.5f * (zi - yi);
        float Dr = zr - yr, Di = zi + yi;
        float Xor = 0.5f * Di, Xoi = -0.5f * Dr;     // -i*D/2
        float xv = (float)k * (1.0f / 512.0f);       // e^{-2pi i k/512} = (tc, -ts)
        float tc = cosr(xv), ts = sinr(xv);
        float Xre = Xer + tc * Xor + ts * Xoi;
        float Xim = Xei + tc * Xoi - ts * Xor;
        if (k == 0) Xim = 0.f;
        float r2 = Xre * Xre + Xim * Xim;
        float c, s;
        if (r2 > 1e-30f) {
            float inv = __builtin_amdgcn_rsqf(r2);
            c = Xre * inv; s = Xim * inv;
        } else { c = 1.f; s = 0.f; }                 // atan2(0,0)=0 -> (1,0)
        float m = magp[k];
        Br[P(k)] = m * c;
        Bi[P(k)] = m * s;
    }
    if (lane == 0) {
        float v = Ar[P(0)] - Ai[P(0)];               // Nyquist bin (real)
        Br[P(256)] = (v >= 0.f) ? magp[256] : -magp[256];
        Bi[P(256)] = 0.f;
    }
    wsync();
    spec_to_frame(Ar, Ai, Br, Bi, swin2, lane, frames + (size_t)frame * NFFT);
}

// ============================================================
// K_ola: overlap-add + NOLA normalize (+ reflect-pad for mode 0)
// ============================================================
__global__ __launch_bounds__(256) void k_ola(const float* __restrict__ frames,
                                             const float* __restrict__ wsqi,
                                             float* __restrict__ out, int mode) {
    int plen = mode ? LOUT : XPLEN;
    long long gid = (long long)blockIdx.x * 256 + threadIdx.x;
    if (gid >= (long long)BATCH * plen) return;
    int b = (int)(gid / plen), p = (int)(gid % plen);
    int q = mode ? p : p - 256;
    if (q < 0) q = -q;
    else if (q >= LOUT) q = 2 * LOUT - 2 - q;
    int n = q + 256;
    int tmax = n / HOP; if (tmax > TFRAMES - 1) tmax = TFRAMES - 1;
    int tmin = (n - (NFFT - 1) + (HOP - 1)) / HOP; if (tmin < 0) tmin = 0;
    const float* fb = frames + (size_t)b * TFRAMES * NFFT;
    float acc = 0.f;
    for (int t = tmin; t <= tmax; ++t) acc += fb[(size_t)t * NFFT + (n - t * HOP)];
    out[gid] = acc * wsqi[n];
}

// ============================================================
extern "C" void kernel_launch(void* const* d_in, const int* in_sizes, int n_in,
                              void* d_out, int out_size, void* d_ws, size_t ws_size,
                              hipStream_t stream) {
    const float* mag  = (const float*)d_in[0];
    const float* ang0 = (const float*)d_in[1];
    const float* win  = (const float*)d_in[2];
    float* ws     = (float*)d_ws;
    float* frames = ws + OFF_FRAMES;
    float* xp     = ws + OFF_XP;
    float* wsqi   = ws + OFF_WSQI;
    float* outp   = (float*)d_out;

    k_init<<<(XPLEN + 255) / 256, 256, 0, stream>>>(win, wsqi);

    const int fblocks = BATCH * TFRAMES / 4;   // 8192
    k_inv0<<<fblocks, 256, 0, stream>>>(mag, ang0, win, frames);
    for (int it = 0; it < NITER; ++it) {
        k_ola<<<(BATCH * XPLEN + 255) / 256, 256, 0, stream>>>(frames, wsqi, xp, 0);
        k_fused<<<fblocks, 256, 0, stream>>>(xp, mag, win, frames);
    }
    k_ola<<<(BATCH * LOUT + 255) / 256, 256, 0, stream>>>(frames, wsqi, outp, 1);
}

// Round 3
// 2172.165 us; speedup vs baseline: 1.4537x; 1.0472x over previous
//
#include <hip/hip_runtime.h>
#include <math.h>

#define BATCH 32
#define TFRAMES 1024
#define NBINS 257
#define NFFT 512
#define HOP 160
#define LOUT 163680
#define XPLEN 164192
#define NITER 32
#define FPW 8                       // frames per wave (strip)
#define STRIDE (FPW*HOP)            // 1280
#define SPAN (STRIDE + NFFT - HOP)  // 1632
#define HALO (NFFT - HOP)           // 352
#define BXP ((size_t)BATCH*XPLEN)   // 5254144 floats per buffer

#define P(i) ((i) + ((i) >> 5))     // LDS pad: 2-way max on stride-1/64 patterns

__device__ __forceinline__ float cosr(float x){ return __builtin_amdgcn_cosf(x); }
__device__ __forceinline__ float sinr(float x){ return __builtin_amdgcn_sinf(x); }
__device__ __forceinline__ void wsync(){
    __builtin_amdgcn_fence(__ATOMIC_SEQ_CST, "wavefront");
    __builtin_amdgcn_wave_barrier();
}

struct Tw { float c1,s1,c2,s2,c3,s3; };
__device__ __forceinline__ Tw twset(float x){
    Tw t; float c=cosr(x), s=sinr(x);
    t.c1=c; t.s1=s;
    t.c2=c*c-s*s; t.s2=2.f*c*s;
    t.c3=t.c2*c-t.s2*s; t.s3=t.c2*s+t.s2*c;
    return t;
}

template<int SIGN, bool TWID>
__device__ __forceinline__ void bfly4(const float xr[4], const float xi[4],
                                      const Tw& t, float yr[4], float yi[4]){
    constexpr float SG = (SIGN>0)?1.f:-1.f;
    float apc_r=xr[0]+xr[2], apc_i=xi[0]+xi[2];
    float amc_r=xr[0]-xr[2], amc_i=xi[0]-xi[2];
    float bpd_r=xr[1]+xr[3], bpd_i=xi[1]+xi[3];
    float bmd_r=xr[1]-xr[3], bmd_i=xi[1]-xi[3];
    yr[0]=apc_r+bpd_r; yi[0]=apc_i+bpd_i;
    float u2r=apc_r-bpd_r, u2i=apc_i-bpd_i;
    float u1r=amc_r-SG*bmd_i, u1i=amc_i+SG*bmd_r;
    float u3r=amc_r+SG*bmd_i, u3i=amc_i-SG*bmd_r;
    if (TWID){
        float s1=SG*t.s1, s2=SG*t.s2, s3=SG*t.s3;
        yr[1]=t.c1*u1r-s1*u1i; yi[1]=t.c1*u1i+s1*u1r;
        yr[2]=t.c2*u2r-s2*u2i; yi[2]=t.c2*u2i+s2*u2r;
        yr[3]=t.c3*u3r-s3*u3i; yi[3]=t.c3*u3i+s3*u3r;
    } else {
        yr[1]=u1r; yi[1]=u1i; yr[2]=u2r; yi[2]=u2i; yr[3]=u3r; yi[3]=u3i;
    }
}

// 256-pt complex FFT, regs in (element lane+64c), regs out (natural order).
// lev0 from regs (q=0), lev3 to regs (unit twiddles).
template<int SIGN>
__device__ __forceinline__ void fft256reg(float xr[4], float xi[4],
                                          float* t0r, float* t0i,
                                          float* t1r, float* t1i,
                                          const Tw& tw0, const Tw& tw1, const Tw& tw2,
                                          int lane){
    float yr[4], yi[4], ar[4], ai[4];
    bfly4<SIGN,true>(xr, xi, tw0, yr, yi);
    wsync();
    { int o = 4*lane;
#pragma unroll
      for (int c=0;c<4;++c){ t0r[P(o+c)]=yr[c]; t0i[P(o+c)]=yi[c]; } }
    wsync();
#pragma unroll
    for (int c=0;c<4;++c){ ar[c]=t0r[P(lane+64*c)]; ai[c]=t0i[P(lane+64*c)]; }
    bfly4<SIGN,true>(ar, ai, tw1, yr, yi);
    wsync();
    { int o = (lane&3) + 16*(lane>>2);
#pragma unroll
      for (int c=0;c<4;++c){ t1r[P(o+4*c)]=yr[c]; t1i[P(o+4*c)]=yi[c]; } }
    wsync();
#pragma unroll
    for (int c=0;c<4;++c){ ar[c]=t1r[P(lane+64*c)]; ai[c]=t1i[P(lane+64*c)]; }
    bfly4<SIGN,true>(ar, ai, tw2, yr, yi);
    wsync();
    { int o = (lane&15) + 64*(lane>>4);
#pragma unroll
      for (int c=0;c<4;++c){ t0r[P(o+16*c)]=yr[c]; t0i[P(o+16*c)]=yi[c]; } }
    wsync();
#pragma unroll
    for (int c=0;c<4;++c){ ar[c]=t0r[P(lane+64*c)]; ai[c]=t0i[P(lane+64*c)]; }
    bfly4<SIGN,false>(ar, ai, tw0, xr, xi);
}

// ============================================================
// k_init: wsqi (NOLA inverse) + zero X0,X1
// ============================================================
__global__ __launch_bounds__(256) void k_init(const float* __restrict__ win,
                                              float* __restrict__ wsqi,
                                              float4* __restrict__ Z){
    int gid = blockIdx.x*256 + threadIdx.x;
    int stride = gridDim.x*256;
    float4 z4 = make_float4(0.f,0.f,0.f,0.f);
    for (int u = gid; u < (int)(2*BXP/4); u += stride) Z[u] = z4;
    for (int i = gid; i < XPLEN; i += stride){
        int n = i;
        int tmax = n / HOP; if (tmax > TFRAMES-1) tmax = TFRAMES-1;
        int tmin = (n - (NFFT-1) + (HOP-1)) / HOP; if (tmin < 0) tmin = 0;
        float acc = 0.f;
        for (int t = tmin; t <= tmax; ++t){ float w = win[n - t*HOP]; acc += w*w; }
        wsqi[i] = 1.0f / (acc > 1e-11f ? acc : 1.0f);
    }
}

// shared istft tail: S regs -> c2r pack -> inv FFT -> window -> OLA -> strip store
__device__ __forceinline__ void istft_tail(float sr_[4], float si_[4],
                                           float* t0r, float* t0i, float* t1r, float* t1i,
                                           const Tw& tw0, const Tw& tw1, const Tw& tw2,
                                           const float twc[4], const float tws[4],
                                           const float wA[4], const float wB[4],
                                           int lane, int f, float2* sa2){
    float pr[4], pi[4];
#pragma unroll
    for (int c=0;c<4;++c){
        int k = lane + 64*c;
        float yr = t1r[P(256-k)], yi = t1i[P(256-k)];
        float Xer = 0.5f*(sr_[c]+yr), Xei = 0.5f*(si_[c]-yi);
        float Dr = sr_[c]-yr, Di = si_[c]+yi;
        float Xor = 0.5f*(twc[c]*Dr - tws[c]*Di);
        float Xoi = 0.5f*(twc[c]*Di + tws[c]*Dr);
        pr[c] = Xer - Xoi;
        pi[c] = Xei + Xor;
    }
    fft256reg<+1>(pr, pi, t0r,t0i,t1r,t1i, tw0,tw1,tw2, lane);
    constexpr float SC = 1.f/256.f;
    int base2 = f*(HOP/2);
#pragma unroll
    for (int c=0;c<4;++c){
        int u = base2 + lane + 64*c;
        float2 v = sa2[u];
        v.x += pr[c]*wA[c]*SC;
        v.y += pi[c]*wB[c]*SC;
        sa2[u] = v;
    }
    wsync();
}

__device__ __forceinline__ void strip_store(float* __restrict__ Xw, int b, int si,
                                            float2* sa2, int lane){
    float* Xnb = Xw + (size_t)b*XPLEN + (size_t)si*STRIDE;
    float2* Xn2 = (float2*)Xnb;
    const float* saF = (const float*)sa2;
#pragma unroll
    for (int j=0;j<8;++j){ int u = HALO/2 + lane + 64*j; if (u < STRIDE/2) Xn2[u] = sa2[u]; }
#pragma unroll
    for (int j=0;j<6;++j){ int i = lane + 64*j; if (i < HALO) unsafeAtomicAdd(Xnb+i, saF[i]); }
#pragma unroll
    for (int j=0;j<6;++j){ int i = STRIDE + lane + 64*j; if (i < SPAN) unsafeAtomicAdd(Xnb+i, saF[i]); }
}

// ============================================================
// k_gl: one Griffin-Lim iteration. wave = strip of 8 frames.
// reads Xr (prev OLA acc), writes Xw (OLA acc), zeroes Xz (rotation).
// ============================================================
__global__ __launch_bounds__(128,4) void k_gl(const float* __restrict__ Xr,
                                              float* __restrict__ Xw,
                                              float* __restrict__ Xz,
                                              const float* __restrict__ mag,
                                              const float* __restrict__ win,
                                              const float* __restrict__ wsq){
    __shared__ float T0r[2][272], T0i[2][272], T1r[2][272], T1i[2][272];
    __shared__ float2 sacc[2][SPAN/2];
    int tid = threadIdx.x, w = tid>>6, lane = tid&63;
    int b = blockIdx.y;
    int si = blockIdx.x*2 + w;
    int t0 = si*FPW;

    // zero rotation buffer (read last iteration, written next iteration)
    {
        float4 z4 = make_float4(0.f,0.f,0.f,0.f);
        int gid = (b*64 + blockIdx.x)*128 + tid;        // 262144 threads
        float4* C4 = (float4*)Xz;
        const int TOT4 = (int)(BXP/4);
#pragma unroll
        for (int j=0;j<6;++j){ int u = gid + j*262144; if (u < TOT4) C4[u]=z4; }
    }

    float *t0r=T0r[w], *t0i=T0i[w], *t1r=T1r[w], *t1i=T1i[w];
    float2* sa2 = sacc[w];

    // per-wave constants (no trig in frame loop)
    Tw tw0 = twset((float)lane * (1.f/256.f));
    Tw tw1 = twset((float)(lane>>2) * (1.f/64.f));
    Tw tw2 = twset((float)(lane>>4) * (1.f/16.f));
    float twc[4], tws[4], wA[4], wB[4];
#pragma unroll
    for (int c=0;c<4;++c){
        int k = lane + 64*c;
        float x = (float)k * (1.f/512.f);
        twc[c]=cosr(x); tws[c]=sinr(x);
        float2 wv = ((const float2*)win)[k];
        wA[c]=wv.x; wB[c]=wv.y;
    }
#pragma unroll
    for (int j=0;j<13;++j){ int u = lane + 64*j; if (u < SPAN/2) sa2[u]=make_float2(0.f,0.f); }

    const float* Xb = Xr + (size_t)b*XPLEN;
    const float* magb = mag + ((size_t)b*TFRAMES)*NBINS;

#pragma unroll 1
    for (int f=0; f<FPW; ++f){
        int t = t0 + f;
        float fr[4], fi[4];
        bool edge = (t < 2) | (t >= TFRAMES-2);
        if (!edge){
            const float2* a2 = (const float2*)(Xb + (size_t)t*HOP);
            const float2* q2 = (const float2*)(wsq + (size_t)t*HOP);
#pragma unroll
            for (int c=0;c<4;++c){
                int m = lane + 64*c;
                float2 av = a2[m], qv = q2[m];
                fr[c] = av.x*qv.x*wA[c];
                fi[c] = av.y*qv.y*wB[c];
            }
        } else {
#pragma unroll
            for (int c=0;c<4;++c){
                int m = lane + 64*c;
                int p0 = t*HOP + 2*m, p1 = p0+1;
                int n0 = (p0<256)?(512-p0):((p0>=LOUT+256)?(2*LOUT+510-p0):p0);
                int n1 = (p1<256)?(512-p1):((p1>=LOUT+256)?(2*LOUT+510-p1):p1);
                fr[c] = Xb[n0]*wsq[n0]*wA[c];
                fi[c] = Xb[n1]*wsq[n1]*wB[c];
            }
        }
        // forward FFT of packed frame
        fft256reg<-1>(fr, fi, t0r,t0i,t1r,t1i, tw0,tw1,tw2, lane);
        float z0r = fr[0], z0i = fi[0];          // lane0: Z[0] for Nyquist
        // mirror exchange for r2c unpack
        wsync();
#pragma unroll
        for (int c=0;c<4;++c){ int k=lane+64*c; t0r[P(k)]=fr[c]; t0i[P(k)]=fi[c]; }
        wsync();
        float sr_[4], si_[4];
        const float* magp = magb + (size_t)t*NBINS;
#pragma unroll
        for (int c=0;c<4;++c){
            int k = lane + 64*c;
            int mk = (256 - k) & 255;
            float yr = t0r[P(mk)], yi = t0i[P(mk)];
            float zr = fr[c], zi = fi[c];
            float Xer = 0.5f*(zr+yr), Xei = 0.5f*(zi-yi);
            float Dr = zr-yr, Di = zi+yi;
            float Xor = 0.5f*Di, Xoi = -0.5f*Dr;
            float Xre = Xer + twc[c]*Xor + tws[c]*Xoi;
            float Xim = Xei + twc[c]*Xoi - tws[c]*Xor;
            if (c==0 && lane==0) Xim = 0.f;
            float r2 = Xre*Xre + Xim*Xim;
            bool ok = (r2 > 1e-30f);
            float inv = ok ? __builtin_amdgcn_rsqf(r2) : 0.f;
            float cc = ok ? Xre*inv : 1.f;
            float ss = Xim*inv;
            float m = magp[k];
            sr_[c] = m*cc; si_[c] = m*ss;
        }
        // stage S (+Nyquist) for the c2r pack mirror
        wsync();
#pragma unroll
        for (int c=0;c<4;++c){ int k=lane+64*c; t1r[P(k)]=sr_[c]; t1i[P(k)]=si_[c]; }
        if (lane==0){
            float v = z0r - z0i;
            t1r[P(256)] = (v>=0.f)? magp[256] : -magp[256];
            t1i[P(256)] = 0.f;
        }
        wsync();
        istft_tail(sr_, si_, t0r,t0i,t1r,t1i, tw0,tw1,tw2, twc,tws, wA,wB, lane, f, sa2);
    }
    strip_store(Xw, b, si, sa2, lane);
}

// ============================================================
// k_inv0s: iteration-0 istft from (mag, angles_init), strip OLA
// ============================================================
__global__ __launch_bounds__(128,4) void k_inv0s(const float* __restrict__ mag,
                                                 const float* __restrict__ ang,
                                                 const float* __restrict__ win,
                                                 float* __restrict__ Xw){
    __shared__ float T0r[2][272], T0i[2][272], T1r[2][272], T1i[2][272];
    __shared__ float2 sacc[2][SPAN/2];
    int tid = threadIdx.x, w = tid>>6, lane = tid&63;
    int b = blockIdx.y;
    int si = blockIdx.x*2 + w;
    int t0 = si*FPW;

    float *t0r=T0r[w], *t0i=T0i[w], *t1r=T1r[w], *t1i=T1i[w];
    float2* sa2 = sacc[w];

    Tw tw0 = twset((float)lane * (1.f/256.f));
    Tw tw1 = twset((float)(lane>>2) * (1.f/64.f));
    Tw tw2 = twset((float)(lane>>4) * (1.f/16.f));
    float twc[4], tws[4], wA[4], wB[4];
#pragma unroll
    for (int c=0;c<4;++c){
        int k = lane + 64*c;
        float x = (float)k * (1.f/512.f);
        twc[c]=cosr(x); tws[c]=sinr(x);
        float2 wv = ((const float2*)win)[k];
        wA[c]=wv.x; wB[c]=wv.y;
    }
#pragma unroll
    for (int j=0;j<13;++j){ int u = lane + 64*j; if (u < SPAN/2) sa2[u]=make_float2(0.f,0.f); }

    const float* magb = mag + ((size_t)b*TFRAMES)*NBINS;
    const float* angb = ang + ((size_t)b*TFRAMES)*NBINS;

#pragma unroll 1
    for (int f=0; f<FPW; ++f){
        int t = t0 + f;
        const float* magp = magb + (size_t)t*NBINS;
        const float* angp = angb + (size_t)t*NBINS;
        float sr_[4], si_[4];
#pragma unroll
        for (int c=0;c<4;++c){
            int k = lane + 64*c;
            float m = magp[k], a = angp[k];
            float sn, cs;
            sincosf(a, &sn, &cs);
            sr_[c] = m*cs;
            si_[c] = (c==0 && lane==0) ? 0.f : m*sn;
        }
        wsync();
#pragma unroll
        for (int c=0;c<4;++c){ int k=lane+64*c; t1r[P(k)]=sr_[c]; t1i[P(k)]=si_[c]; }
        if (lane==0){
            t1r[P(256)] = magp[256]*cosf(angp[256]);
            t1i[P(256)] = 0.f;
        }
        wsync();
        istft_tail(sr_, si_, t0r,t0i,t1r,t1i, tw0,tw1,tw2, twc,tws, wA,wB, lane, f, sa2);
    }
    strip_store(Xw, b, si, sa2, lane);
}

// ============================================================
// k_out: normalize + crop
// ============================================================
__global__ __launch_bounds__(128) void k_out(const float* __restrict__ X,
                                             const float* __restrict__ wsq,
                                             float* __restrict__ out){
    int b = blockIdx.y;
    int idx = blockIdx.x*128 + threadIdx.x;
    if (idx >= LOUT/2) return;
    const float2* Xp = (const float2*)(X + (size_t)b*XPLEN + 256);
    const float2* Qp = (const float2*)(wsq + 256);
    float2 v = Xp[idx], q = Qp[idx];
    ((float2*)(out + (size_t)b*LOUT))[idx] = make_float2(v.x*q.x, v.y*q.y);
}

// ============================================================
extern "C" void kernel_launch(void* const* d_in, const int* in_sizes, int n_in,
                              void* d_out, int out_size, void* d_ws, size_t ws_size,
                              hipStream_t stream) {
    const float* mag  = (const float*)d_in[0];
    const float* ang0 = (const float*)d_in[1];
    const float* win  = (const float*)d_in[2];
    float* ws = (float*)d_ws;
    float* X[3] = { ws, ws + BXP, ws + 2*BXP };
    float* wsqi = ws + 3*BXP;
    float* outp = (float*)d_out;

    k_init<<<4096, 256, 0, stream>>>(win, wsqi, (float4*)ws);   // wsqi + zero X0,X1

    dim3 g(64, BATCH);
    k_inv0s<<<g, 128, 0, stream>>>(mag, ang0, win, X[0]);
    for (int it = 0; it < NITER; ++it){
        k_gl<<<g, 128, 0, stream>>>(X[it%3], X[(it+1)%3], X[(it+2)%3], mag, win, wsqi);
    }
    k_out<<<dim3(640, BATCH), 128, 0, stream>>>(X[NITER%3], wsqi, outp);
}